// Round 8
// baseline (56.561 us; speedup 1.0000x reference)
//
#include <hip/hip_runtime.h>
#include <cstddef>
#include <cstdint>

#define B_    8
#define T_EN_ 512
#define T_DE_ 128
#define D_    512
#define U_    256

// tanh(x) = 1 - 2/(exp2(C*x)+1), C = 2*log2(e)
#define TANH_C 2.8853900817779268f
#define L2E_   1.4426950408889634f
#define TANH_CLAMP 0.99999994f

typedef float f32x4 __attribute__((ext_vector_type(4)));
typedef short s16x8 __attribute__((ext_vector_type(8)));

__device__ __forceinline__ float fast_tanh_clamped(float x) {
  const float e = __builtin_amdgcn_exp2f(x * TANH_C);
  float t = fmaf(-2.0f, __builtin_amdgcn_rcpf(e + 1.0f), 1.0f);
  return fminf(fmaxf(t, -TANH_CLAMP), TANH_CLAMP);
}

// split f32 -> bf16 hi (truncated) + bf16 lo (truncated remainder)
__device__ __forceinline__ void split_bf16(float x, short& hi, short& lo) {
  const unsigned u = __float_as_uint(x);
  hi = (short)(u >> 16);
  const float hf = __uint_as_float(u & 0xffff0000u);
  const float lf = x - hf;
  lo = (short)(__float_as_uint(lf) >> 16);
}

// ---------------------------------------------------------------------------
// K0: prepack w_en / w_de to bf16 hi/lo fragment planes (verified r5/r6 code).
// k-map within a 32-k step s: k = s*32 + g*4 + (e&3) + 16*(e>>2), lane=g*16+n.
// unit idx = ((s*16 + US)*4 + g)*16 + n ; frag shorts at unit*8.
// grid 128 x 256: blk<64 -> w_en, else w_de. One s16x8 pair per thread.
// ---------------------------------------------------------------------------
__global__ __launch_bounds__(256) void wprep_kernel(
    const float* __restrict__ w_en, const float* __restrict__ w_de,
    short* __restrict__ wen_hi, short* __restrict__ wen_lo,
    short* __restrict__ wde_hi, short* __restrict__ wde_lo) {
  const int blk = blockIdx.x, tid = threadIdx.x;
  const bool is_en = blk < 64;
  const int wq = blk & 63;
  const int s = wq >> 2, USq = wq & 3;
  const int n = tid & 15, g = (tid >> 4) & 3;
  const int US = USq * 4 + (tid >> 6);
  const float* W = is_en ? w_en : w_de;
  short* ph = is_en ? wen_hi : wde_hi;
  short* pl = is_en ? wen_lo : wde_lo;
  s16x8 h8, l8;
  #pragma unroll
  for (int e = 0; e < 8; ++e) {
    const int k = s * 32 + g * 4 + (e & 3) + 16 * (e >> 2);
    short h, l;
    split_bf16(W[(size_t)k * U_ + US * 16 + n], h, l);
    h8[e] = h; l8[e] = l;
  }
  const size_t ub = ((size_t)(s * 16 + US) * 4 + g) * 16 + n;
  *(s16x8*)(ph + ub * 8) = h8;
  *(s16x8*)(pl + ub * 8) = l8;
}

// ---------------------------------------------------------------------------
// K1: fused projection. Per block: stage 32 activation rows (f32, 64 KB read)
// -> split-bf16 FRAGMENT layout in LDS (2 planes x 32 KB, XOR-swizzled), then
// K-loop: w-frags per-lane from global planes (L2-hot), x-frags from LDS.
// Block = 128u (uh half) x 32 rows; 4 waves by u: wave = 32u x 32rows,
// acc[usub 2][isub 2] f32x4. 12 MFMA/step (hh, hl, lh), 16 steps.
// grid 320: blk<64 -> de (tile = blk>>1 in [0,32), uh = blk&1; rows = flat
// 1024 de rows); else en (y=blk-64: b=y>>5, uh=(y>>4)&1, i0=(y&15)*32).
// en: D[u][i] -> Et[b][u][i]. de: D[u][j] -> de_t[j][u] (scalar scatter).
// C/D layout (HW-verified r5/r6): col = lane&15 (B-op), row = (lane>>4)*4+reg.
// ---------------------------------------------------------------------------
__global__ __launch_bounds__(256) void proj_fused_kernel(
    const float* __restrict__ en, const float* __restrict__ de,
    const short* __restrict__ wen_hi, const short* __restrict__ wen_lo,
    const short* __restrict__ wde_hi, const short* __restrict__ wde_lo,
    float* __restrict__ Et, float* __restrict__ de_t) {
  __shared__ short xf_hi[16384];   // [s2i 32][lane 64][e 8] shorts, 32 KB
  __shared__ short xf_lo[16384];

  const int tid = threadIdx.x, lane = tid & 63, wv = tid >> 6;
  const int blk = blockIdx.x;
  const bool deb = blk < 64;
  const float* X;
  const short *Whi, *Wlo;
  int b = 0, i0, uh;
  if (deb) {
    const int jt = blk >> 1; uh = blk & 1; i0 = jt * 32;   // jt in [0,32)
    X = de + (size_t)i0 * D_;                              // flat de rows
    Whi = wde_hi; Wlo = wde_lo;
  } else {
    const int y = blk - 64;
    b = y >> 5; uh = (y >> 4) & 1;
    i0 = (y & 15) * 32;
    X = en + ((size_t)b * T_EN_ + i0) * D_;
    Whi = wen_hi; Wlo = wen_lo;
  }

  // ---- stage & convert: thread owns row r = tid>>3, k-span (tid&7)*64 ----
  {
    const int r = tid >> 3, kh = tid & 7;
    const int isub = r >> 4, n = r & 15;
    const float* src = X + (size_t)r * D_ + kh * 64;
    #pragma unroll
    for (int c = 0; c < 2; ++c) {               // two 32-k steps
      const int s2i = (kh * 2 + c) * 2 + isub;  // frag-unit index
      float v[32];
      #pragma unroll
      for (int q = 0; q < 8; ++q) {
        const float4 f = *(const float4*)(src + c * 32 + q * 4);
        v[q * 4 + 0] = f.x; v[q * 4 + 1] = f.y;
        v[q * 4 + 2] = f.z; v[q * 4 + 3] = f.w;
      }
      #pragma unroll
      for (int g = 0; g < 4; ++g) {
        s16x8 h8, l8;
        #pragma unroll
        for (int e = 0; e < 8; ++e) {
          const int mm = (e >> 2) * 16 + g * 4 + (e & 3);  // same k-map as w
          short h, l;
          split_bf16(v[mm], h, l);
          h8[e] = h; l8[e] = l;
        }
        // short-index; XOR-swizzle by s2i bits so concurrent writes spread banks
        const int idx = ((s2i * 64 + g * 16 + n) * 8) ^ (((s2i >> 2) & 7) << 3);
        *(s16x8*)(xf_hi + idx) = h8;
        *(s16x8*)(xf_lo + idx) = l8;
      }
    }
  }
  __syncthreads();

  const int US0 = uh * 8 + wv * 2;
  const int rl = lane >> 4, cl = lane & 15;
  f32x4 acc[2][2] = {};

  #pragma unroll 2
  for (int s = 0; s < 16; ++s) {
    const size_t o0 = ((size_t)(s * 16 + US0) * 64 + lane) * 8;
    const s16x8 wh0 = *(const s16x8*)(Whi + o0);
    const s16x8 wl0 = *(const s16x8*)(Wlo + o0);
    const s16x8 wh1 = *(const s16x8*)(Whi + o0 + 512);
    const s16x8 wl1 = *(const s16x8*)(Wlo + o0 + 512);
    const int s20 = s * 2, s21 = s * 2 + 1;
    const int ei0 = ((s20 * 64 + lane) * 8) ^ (((s20 >> 2) & 7) << 3);
    const int ei1 = ((s21 * 64 + lane) * 8) ^ (((s21 >> 2) & 7) << 3);
    const s16x8 eh0 = *(const s16x8*)(xf_hi + ei0);
    const s16x8 el0 = *(const s16x8*)(xf_lo + ei0);
    const s16x8 eh1 = *(const s16x8*)(xf_hi + ei1);
    const s16x8 el1 = *(const s16x8*)(xf_lo + ei1);

    acc[0][0] = __builtin_amdgcn_mfma_f32_16x16x32_bf16(wh0, eh0, acc[0][0], 0, 0, 0);
    acc[0][0] = __builtin_amdgcn_mfma_f32_16x16x32_bf16(wh0, el0, acc[0][0], 0, 0, 0);
    acc[0][0] = __builtin_amdgcn_mfma_f32_16x16x32_bf16(wl0, eh0, acc[0][0], 0, 0, 0);
    acc[0][1] = __builtin_amdgcn_mfma_f32_16x16x32_bf16(wh0, eh1, acc[0][1], 0, 0, 0);
    acc[0][1] = __builtin_amdgcn_mfma_f32_16x16x32_bf16(wh0, el1, acc[0][1], 0, 0, 0);
    acc[0][1] = __builtin_amdgcn_mfma_f32_16x16x32_bf16(wl0, eh1, acc[0][1], 0, 0, 0);
    acc[1][0] = __builtin_amdgcn_mfma_f32_16x16x32_bf16(wh1, eh0, acc[1][0], 0, 0, 0);
    acc[1][0] = __builtin_amdgcn_mfma_f32_16x16x32_bf16(wh1, el0, acc[1][0], 0, 0, 0);
    acc[1][0] = __builtin_amdgcn_mfma_f32_16x16x32_bf16(wl1, eh0, acc[1][0], 0, 0, 0);
    acc[1][1] = __builtin_amdgcn_mfma_f32_16x16x32_bf16(wh1, eh1, acc[1][1], 0, 0, 0);
    acc[1][1] = __builtin_amdgcn_mfma_f32_16x16x32_bf16(wh1, el1, acc[1][1], 0, 0, 0);
    acc[1][1] = __builtin_amdgcn_mfma_f32_16x16x32_bf16(wl1, eh1, acc[1][1], 0, 0, 0);
  }

  #pragma unroll
  for (int us = 0; us < 2; ++us) {
    #pragma unroll
    for (int is = 0; is < 2; ++is) {
      #pragma unroll
      for (int r = 0; r < 4; ++r) {
        const float t = fast_tanh_clamped(acc[us][is][r]);
        const int u = (US0 + us) * 16 + rl * 4 + r;
        const int rw = i0 + is * 16 + cl;     // i (en) or flat j (de)
        if (!deb) Et[((size_t)b * U_ + u) * T_EN_ + rw] = t;
        else      de_t[(size_t)rw * U_ + u] = t;
      }
    }
  }
}

// ---------------------------------------------------------------------------
// K2 v3: mu = sum_u (A+E)*nu/(1+A*E); masked softmax.
// grid 256 = jg*8 + b (b-pinned per XCD), 512 thr = 8 waves.
// Wave w = i-octant: i = w*64 + lane (1 i per lane, dword E loads).
// Each wave computes ALL 4 j of jg -> E read once per 4 j (128 MB total L2).
// Per-u operands {A0..A3}, {A*nu}, nu staged in LDS once, read as b128
// broadcasts. 17 VALU (incl. 4 rcp) per u per lane.
// ---------------------------------------------------------------------------
__global__ __launch_bounds__(512) void attn_mu_softmax_kernel(
    const float* __restrict__ Et, const float* __restrict__ de_t,
    const float* __restrict__ nu, const int* __restrict__ mask,
    float* __restrict__ out) {
  __shared__ f32x4 Ap_s[U_];        // {A0,A1,A2,A3}        4 KB
  __shared__ f32x4 An_s[U_];        // {A0*nu,...}          4 KB
  __shared__ f32x4 nv_s[U_ / 4];    // packed nu            1 KB
  __shared__ float mu_s[4][T_EN_];  // logits               8 KB

  const int tid  = threadIdx.x;
  const int lane = tid & 63;
  const int w    = tid >> 6;          // 0..7 = i-octant
  const int b    = blockIdx.x & 7;
  const int jg   = blockIdx.x >> 3;   // 0..31

  // ---- prologue: stage per-u operands ----
  if (tid < 256) {
    const int u = tid;
    const float nv = nu[u];
    const float* dp = de_t + (size_t)(b * T_DE_ + jg * 4) * U_ + u;
    f32x4 A, An;
    #pragma unroll
    for (int jj = 0; jj < 4; ++jj) {
      A[jj] = dp[(size_t)jj * U_];
      An[jj] = A[jj] * nv;
    }
    Ap_s[u] = A;
    An_s[u] = An;
  } else if (tid < 320) {
    const int t = tid - 256;
    const float4 v = *(const float4*)(nu + t * 4);
    f32x4 n4; n4[0] = v.x; n4[1] = v.y; n4[2] = v.z; n4[3] = v.w;
    nv_s[t] = n4;
  }
  __syncthreads();

  const float* __restrict__ Eb = Et + (size_t)b * U_ * T_EN_ + w * 64 + lane;

  f32x4 acc = {0.f, 0.f, 0.f, 0.f};
  float Ea[8], Eb2[8];
  #pragma unroll
  for (int c = 0; c < 8; ++c) Ea[c] = Eb[(size_t)c * T_EN_];

  for (int u0 = 0; u0 < U_; u0 += 8) {
    if (u0 + 8 < U_) {
      #pragma unroll
      for (int c = 0; c < 8; ++c) Eb2[c] = Eb[(size_t)(u0 + 8 + c) * T_EN_];
    }
    const f32x4 n0 = nv_s[u0 / 4], n1 = nv_s[u0 / 4 + 1];
    #pragma unroll
    for (int c = 0; c < 8; ++c) {
      const float E  = Ea[c];
      const f32x4 A  = Ap_s[u0 + c];    // b128 broadcast
      const f32x4 An = An_s[u0 + c];
      const float nv = (c < 4) ? n0[c] : n1[c - 4];
      const float nuE = nv * E;
      #pragma unroll
      for (int jj = 0; jj < 4; ++jj) {
        const float num = An[jj] + nuE;
        const float den = fmaf(A[jj], E, 1.0f);
        acc[jj] = fmaf(num, __builtin_amdgcn_rcpf(den), acc[jj]);
      }
    }
    #pragma unroll
    for (int c = 0; c < 8; ++c) Ea[c] = Eb2[c];
  }

  #pragma unroll
  for (int jj = 0; jj < 4; ++jj) mu_s[jj][w * 64 + lane] = acc[jj];
  __syncthreads();

  // ---- masked softmax: waves 0..3, one j each ----
  if (w < 4) {
    const int jj = jg * 4 + w;
    float vals[8];
    float mx = -3.0e38f;
    #pragma unroll
    for (int k = 0; k < 8; ++k) {
      const int i = lane + 64 * k;
      const float mi = (float)mask[b * T_EN_ + i];
      const float v = fmaf(mi - 1.0f, 1.0e6f, mu_s[w][i]);
      vals[k] = v;
      mx = fmaxf(mx, v);
    }
    #pragma unroll
    for (int off = 32; off; off >>= 1) mx = fmaxf(mx, __shfl_xor(mx, off, 64));
    float sum = 0.0f;
    #pragma unroll
    for (int k = 0; k < 8; ++k) {
      const float e = __builtin_amdgcn_exp2f((vals[k] - mx) * L2E_);
      vals[k] = e;
      sum += e;
    }
    #pragma unroll
    for (int off = 32; off; off >>= 1) sum += __shfl_xor(sum, off, 64);
    const float inv = __builtin_amdgcn_rcpf(sum);
    float* op = out + (size_t)(b * T_DE_ + jj) * T_EN_;
    #pragma unroll
    for (int k = 0; k < 8; ++k) op[lane + 64 * k] = vals[k] * inv;
  }
}

// ---------------------------------------------------------------------------
extern "C" void kernel_launch(void* const* d_in, const int* in_sizes, int n_in,
                              void* d_out, int out_size, void* d_ws, size_t ws_size,
                              hipStream_t stream) {
  const float* en   = (const float*)d_in[0];   // [B, T_EN, D]
  const float* de   = (const float*)d_in[1];   // [B, T_DE, D]
  const int*   mask = (const int*)d_in[2];     // [B, T_EN]
  const float* w_en = (const float*)d_in[3];   // [D, U]
  const float* w_de = (const float*)d_in[4];   // [D, U]
  const float* nu   = (const float*)d_in[5];   // [U, 1]
  float* out = (float*)d_out;                  // [B, T_DE, T_EN]

  // ws layout (6 MB total; ws verified >= 16 MB by rounds 5/6 running MFMA path)
  float* Et     = (float*)d_ws;                       // [B][U][T_EN]   4 MB
  float* de_t   = Et + (size_t)B_ * U_ * T_EN_;       // [B*T_DE][U]    1 MB
  short* p      = (short*)(de_t + (size_t)B_ * T_DE_ * U_);   // full 1024 rows
  short* wen_hi = p;  p += 131072;                    // D*U shorts each (256 KB)
  short* wen_lo = p;  p += 131072;
  short* wde_hi = p;  p += 131072;
  short* wde_lo = p;  p += 131072;

  wprep_kernel<<<dim3(128), 256, 0, stream>>>(
      w_en, w_de, wen_hi, wen_lo, wde_hi, wde_lo);
  proj_fused_kernel<<<dim3(320), 256, 0, stream>>>(
      en, de, wen_hi, wen_lo, wde_hi, wde_lo, Et, de_t);
  attn_mu_softmax_kernel<<<dim3(256), 512, 0, stream>>>(
      Et, de_t, nu, mask, out);
}

// Round 9
// 54.179 us; speedup vs baseline: 1.0440x; 1.0440x over previous
//
#include <hip/hip_runtime.h>
#include <cstddef>
#include <cstdint>

#define B_    8
#define T_EN_ 512
#define T_DE_ 128
#define D_    512
#define U_    256

// tanh(x) = 1 - 2/(exp2(C*x)+1), C = 2*log2(e)
#define TANH_C 2.8853900817779268f
#define L2E_   1.4426950408889634f
#define TANH_CLAMP 0.99999994f

typedef float f32x4 __attribute__((ext_vector_type(4)));
typedef short s16x8 __attribute__((ext_vector_type(8)));

__device__ __forceinline__ float fast_tanh_clamped(float x) {
  const float e = __builtin_amdgcn_exp2f(x * TANH_C);
  float t = fmaf(-2.0f, __builtin_amdgcn_rcpf(e + 1.0f), 1.0f);
  return fminf(fmaxf(t, -TANH_CLAMP), TANH_CLAMP);
}

// split f32 -> bf16 hi (truncated) + bf16 lo (truncated remainder)
__device__ __forceinline__ void split_bf16(float x, short& hi, short& lo) {
  const unsigned u = __float_as_uint(x);
  hi = (short)(u >> 16);
  const float hf = __uint_as_float(u & 0xffff0000u);
  const float lf = x - hf;
  lo = (short)(__float_as_uint(lf) >> 16);
}

// ---------------------------------------------------------------------------
// K0: prepack w_en / w_de to bf16 hi/lo fragment planes (verified r5-r8).
// k-map within 32-k step s: k = s*32 + g*4 + (e&3) + 16*(e>>2), lane = g*16+n.
// unit idx = ((s*16 + US)*4 + g)*16 + n ; frag shorts at unit*8.
// ---------------------------------------------------------------------------
__global__ __launch_bounds__(256) void wprep_kernel(
    const float* __restrict__ w_en, const float* __restrict__ w_de,
    short* __restrict__ wen_hi, short* __restrict__ wen_lo,
    short* __restrict__ wde_hi, short* __restrict__ wde_lo) {
  const int blk = blockIdx.x, tid = threadIdx.x;
  const bool is_en = blk < 64;
  const int wq = blk & 63;
  const int s = wq >> 2, USq = wq & 3;
  const int n = tid & 15, g = (tid >> 4) & 3;
  const int US = USq * 4 + (tid >> 6);
  const float* W = is_en ? w_en : w_de;
  short* ph = is_en ? wen_hi : wde_hi;
  short* pl = is_en ? wen_lo : wde_lo;
  s16x8 h8, l8;
  #pragma unroll
  for (int e = 0; e < 8; ++e) {
    const int k = s * 32 + g * 4 + (e & 3) + 16 * (e >> 2);
    short h, l;
    split_bf16(W[(size_t)k * U_ + US * 16 + n], h, l);
    h8[e] = h; l8[e] = l;
  }
  const size_t ub = ((size_t)(s * 16 + US) * 4 + g) * 16 + n;
  *(s16x8*)(ph + ub * 8) = h8;
  *(s16x8*)(pl + ub * 8) = l8;
}

// ---------------------------------------------------------------------------
// K1: fused projection (r8-verified staging/k-map; now u-QUARTER per block for
// occupancy). Block = 64 u x 32 rows, 256 thr (4 waves = 2 u-sub x 2 row-half).
// grid 640: blk<128 -> de (jt = blk>>2 of 32 flat-rows, uq = blk&3);
//           else en (y=blk-128: b=y>>6, it=(y>>2)&15, uq=y&3).
// Per step: 4 w-frag b128 (L2) + 2 x-frag LDS + 6 MFMA (hh,hl,lh).
// C/D layout (HW-verified): col = lane&15 (x-row), row = (lane>>4)*4+reg (u).
// ---------------------------------------------------------------------------
__global__ __launch_bounds__(256) void proj_fused_kernel(
    const float* __restrict__ en, const float* __restrict__ de,
    const short* __restrict__ wen_hi, const short* __restrict__ wen_lo,
    const short* __restrict__ wde_hi, const short* __restrict__ wde_lo,
    float* __restrict__ Et, float* __restrict__ de_t) {
  __shared__ short xf_hi[16384];   // [s2i 32][lane 64][e 8] shorts, 32 KB
  __shared__ short xf_lo[16384];

  const int tid = threadIdx.x, lane = tid & 63, wv = tid >> 6;
  const int blk = blockIdx.x;
  const bool deb = blk < 128;
  const float* X;
  const short *Whi, *Wlo;
  int b = 0, i0, uq;
  if (deb) {
    const int jt = blk >> 2; uq = blk & 3; i0 = jt * 32;   // flat de rows
    X = de + (size_t)i0 * D_;
    Whi = wde_hi; Wlo = wde_lo;
  } else {
    const int y = blk - 128;
    b = y >> 6; i0 = ((y >> 2) & 15) * 32; uq = y & 3;
    X = en + ((size_t)b * T_EN_ + i0) * D_;
    Whi = wen_hi; Wlo = wen_lo;
  }

  // ---- stage & convert (identical to r8): row r = tid>>3, k-span (tid&7)*64
  {
    const int r = tid >> 3, kh = tid & 7;
    const int isub = r >> 4, n = r & 15;
    const float* src = X + (size_t)r * D_ + kh * 64;
    #pragma unroll
    for (int c = 0; c < 2; ++c) {
      const int s2i = (kh * 2 + c) * 2 + isub;
      float v[32];
      #pragma unroll
      for (int q = 0; q < 8; ++q) {
        const float4 f = *(const float4*)(src + c * 32 + q * 4);
        v[q * 4 + 0] = f.x; v[q * 4 + 1] = f.y;
        v[q * 4 + 2] = f.z; v[q * 4 + 3] = f.w;
      }
      #pragma unroll
      for (int g = 0; g < 4; ++g) {
        s16x8 h8, l8;
        #pragma unroll
        for (int e = 0; e < 8; ++e) {
          const int mm = (e >> 2) * 16 + g * 4 + (e & 3);
          short h, l;
          split_bf16(v[mm], h, l);
          h8[e] = h; l8[e] = l;
        }
        const int idx = ((s2i * 64 + g * 16 + n) * 8) ^ (((s2i >> 2) & 7) << 3);
        *(s16x8*)(xf_hi + idx) = h8;
        *(s16x8*)(xf_lo + idx) = l8;
      }
    }
  }
  __syncthreads();

  const int wvu = wv & 1, rh = wv >> 1;
  const int US0 = uq * 4 + wvu * 2;       // u-subtile 0..15 (pairs)
  const int rl = lane >> 4, cl = lane & 15;
  f32x4 acc[2] = {};

  #pragma unroll 2
  for (int s = 0; s < 16; ++s) {
    const size_t o0 = ((size_t)(s * 16 + US0) * 64 + lane) * 8;
    const s16x8 wh0 = *(const s16x8*)(Whi + o0);
    const s16x8 wl0 = *(const s16x8*)(Wlo + o0);
    const s16x8 wh1 = *(const s16x8*)(Whi + o0 + 512);
    const s16x8 wl1 = *(const s16x8*)(Wlo + o0 + 512);
    const int s2 = s * 2 + rh;
    const int ei = ((s2 * 64 + lane) * 8) ^ (((s2 >> 2) & 7) << 3);
    const s16x8 eh = *(const s16x8*)(xf_hi + ei);
    const s16x8 el = *(const s16x8*)(xf_lo + ei);

    acc[0] = __builtin_amdgcn_mfma_f32_16x16x32_bf16(wh0, eh, acc[0], 0, 0, 0);
    acc[0] = __builtin_amdgcn_mfma_f32_16x16x32_bf16(wh0, el, acc[0], 0, 0, 0);
    acc[0] = __builtin_amdgcn_mfma_f32_16x16x32_bf16(wl0, eh, acc[0], 0, 0, 0);
    acc[1] = __builtin_amdgcn_mfma_f32_16x16x32_bf16(wh1, eh, acc[1], 0, 0, 0);
    acc[1] = __builtin_amdgcn_mfma_f32_16x16x32_bf16(wh1, el, acc[1], 0, 0, 0);
    acc[1] = __builtin_amdgcn_mfma_f32_16x16x32_bf16(wl1, eh, acc[1], 0, 0, 0);
  }

  #pragma unroll
  for (int us = 0; us < 2; ++us) {
    #pragma unroll
    for (int r = 0; r < 4; ++r) {
      const float t = fast_tanh_clamped(acc[us][r]);
      const int u = (US0 + us) * 16 + rl * 4 + r;
      const int rw = i0 + rh * 16 + cl;     // i (en) or flat j (de)
      if (!deb) Et[((size_t)b * U_ + u) * T_EN_ + rw] = t;
      else      de_t[(size_t)rw * U_ + u] = t;
    }
  }
}

// ---------------------------------------------------------------------------
// K2 v4: mu = sum_u (A+E)*nu/(1+A*E); masked softmax.
// grid 512 = jg2*8 + b (b pinned per XCD), 512 thr = 8 waves.
// Block: 2 j (jg2*2+{0,1}) x 512 i x 256 u. Wave (uq = w&3, ih = w>>2):
// 2 j x 256 i (4 i/lane, float4 E) x 64 u -> partial mu in LDS, combined in
// the softmax phase. Per u per wave: 1 b128 {A0,A0nu,A1,A1nu} + 1/4 nv b128
// = 1.25 LDS reads for 8 terms/lane (v3 was 2.25 for 4 -> LDS-pipe-bound).
// ---------------------------------------------------------------------------
__global__ __launch_bounds__(512) void attn_mu_softmax_kernel(
    const float* __restrict__ Et, const float* __restrict__ de_t,
    const float* __restrict__ nu, const int* __restrict__ mask,
    float* __restrict__ out) {
  __shared__ f32x4 Lp_s[U_];           // {A0, A0nu, A1, A1nu}  4 KB
  __shared__ f32x4 nv_s[U_ / 4];       // packed nu             1 KB
  __shared__ float mu_p[4][2][T_EN_];  // partial logits       16 KB

  const int tid  = threadIdx.x;
  const int lane = tid & 63;
  const int w    = tid >> 6;           // 0..7
  const int uq   = w & 3;
  const int ih   = w >> 2;
  const int b    = blockIdx.x & 7;
  const int jg   = blockIdx.x >> 3;    // 0..63
  const int j0   = jg * 2;

  // ---- prologue: stage per-u operands ----
  if (tid < 256) {
    const int u = tid;
    const float nv = nu[u];
    const float A0 = de_t[(size_t)(b * T_DE_ + j0) * U_ + u];
    const float A1 = de_t[(size_t)(b * T_DE_ + j0 + 1) * U_ + u];
    f32x4 L;
    L[0] = A0; L[1] = A0 * nv; L[2] = A1; L[3] = A1 * nv;
    Lp_s[u] = L;
  } else if (tid < 320) {
    const int t = tid - 256;
    const float4 v = *(const float4*)(nu + t * 4);
    f32x4 n4; n4[0] = v.x; n4[1] = v.y; n4[2] = v.z; n4[3] = v.w;
    nv_s[t] = n4;
  }
  __syncthreads();

  const int ub = uq * 64;
  const float* __restrict__ Eb =
      Et + ((size_t)b * U_ + ub) * T_EN_ + ih * 256 + lane * 4;

  f32x4 acc0 = {0.f, 0.f, 0.f, 0.f};   // j0
  f32x4 acc1 = {0.f, 0.f, 0.f, 0.f};   // j0+1

  f32x4 La[4], Lb[4], na, nb;
  float4 Ea[4], Eb4[4];

#define LOADC(LB, NB, EB, C0)                                            \
  { _Pragma("unroll")                                                    \
    for (int c = 0; c < 4; ++c) {                                        \
      LB[c] = Lp_s[ub + (C0) + c];                                       \
      EB[c] = *(const float4*)(Eb + (size_t)((C0) + c) * T_EN_);         \
    }                                                                    \
    NB = nv_s[(ub + (C0)) >> 2]; }

#define COMP(LB, NB, EB)                                                 \
  { _Pragma("unroll")                                                    \
    for (int c = 0; c < 4; ++c) {                                        \
      const f32x4 L = LB[c];                                             \
      const float nv = NB[c];                                            \
      const float4 E = EB[c];                                            \
      const float n0 = nv * E.x, n1 = nv * E.y,                          \
                  n2 = nv * E.z, n3 = nv * E.w;                          \
      acc0[0] = fmaf(L[1] + n0,                                          \
                     __builtin_amdgcn_rcpf(fmaf(L[0], E.x, 1.f)), acc0[0]);\
      acc0[1] = fmaf(L[1] + n1,                                          \
                     __builtin_amdgcn_rcpf(fmaf(L[0], E.y, 1.f)), acc0[1]);\
      acc0[2] = fmaf(L[1] + n2,                                          \
                     __builtin_amdgcn_rcpf(fmaf(L[0], E.z, 1.f)), acc0[2]);\
      acc0[3] = fmaf(L[1] + n3,                                          \
                     __builtin_amdgcn_rcpf(fmaf(L[0], E.w, 1.f)), acc0[3]);\
      acc1[0] = fmaf(L[3] + n0,                                          \
                     __builtin_amdgcn_rcpf(fmaf(L[2], E.x, 1.f)), acc1[0]);\
      acc1[1] = fmaf(L[3] + n1,                                          \
                     __builtin_amdgcn_rcpf(fmaf(L[2], E.y, 1.f)), acc1[1]);\
      acc1[2] = fmaf(L[3] + n2,                                          \
                     __builtin_amdgcn_rcpf(fmaf(L[2], E.z, 1.f)), acc1[2]);\
      acc1[3] = fmaf(L[3] + n3,                                          \
                     __builtin_amdgcn_rcpf(fmaf(L[2], E.w, 1.f)), acc1[3]);\
    } }

  LOADC(La, na, Ea, 0)
  for (int c0 = 0; c0 < 64; c0 += 8) {
    LOADC(Lb, nb, Eb4, c0 + 4)
    COMP(La, na, Ea)
    if (c0 + 8 < 64) LOADC(La, na, Ea, c0 + 8)
    COMP(Lb, nb, Eb4)
  }
#undef LOADC
#undef COMP

  *(f32x4*)&mu_p[uq][0][ih * 256 + lane * 4] = acc0;
  *(f32x4*)&mu_p[uq][1][ih * 256 + lane * 4] = acc1;
  __syncthreads();

  // ---- combine partials + masked softmax: waves 0/1, one j each ----
  if (w < 2) {
    const int jj = j0 + w;
    float vals[8];
    float mx = -3.0e38f;
    #pragma unroll
    for (int k = 0; k < 8; ++k) {
      const int i = lane + 64 * k;
      const float s = (mu_p[0][w][i] + mu_p[1][w][i]) +
                      (mu_p[2][w][i] + mu_p[3][w][i]);
      const float mi = (float)mask[b * T_EN_ + i];
      const float v = fmaf(mi - 1.0f, 1.0e6f, s);
      vals[k] = v;
      mx = fmaxf(mx, v);
    }
    #pragma unroll
    for (int off = 32; off; off >>= 1) mx = fmaxf(mx, __shfl_xor(mx, off, 64));
    float sum = 0.0f;
    #pragma unroll
    for (int k = 0; k < 8; ++k) {
      const float e = __builtin_amdgcn_exp2f((vals[k] - mx) * L2E_);
      vals[k] = e;
      sum += e;
    }
    #pragma unroll
    for (int off = 32; off; off >>= 1) sum += __shfl_xor(sum, off, 64);
    const float inv = __builtin_amdgcn_rcpf(sum);
    float* op = out + (size_t)(b * T_DE_ + jj) * T_EN_;
    #pragma unroll
    for (int k = 0; k < 8; ++k) op[lane + 64 * k] = vals[k] * inv;
  }
}

// ---------------------------------------------------------------------------
extern "C" void kernel_launch(void* const* d_in, const int* in_sizes, int n_in,
                              void* d_out, int out_size, void* d_ws, size_t ws_size,
                              hipStream_t stream) {
  const float* en   = (const float*)d_in[0];   // [B, T_EN, D]
  const float* de   = (const float*)d_in[1];   // [B, T_DE, D]
  const int*   mask = (const int*)d_in[2];     // [B, T_EN]
  const float* w_en = (const float*)d_in[3];   // [D, U]
  const float* w_de = (const float*)d_in[4];   // [D, U]
  const float* nu   = (const float*)d_in[5];   // [U, 1]
  float* out = (float*)d_out;                  // [B, T_DE, T_EN]

  // ws layout (6 MB)
  float* Et     = (float*)d_ws;                       // [B][U][T_EN]   4 MB
  float* de_t   = Et + (size_t)B_ * U_ * T_EN_;       // [B*T_DE][U]    1 MB
  short* p      = (short*)(de_t + (size_t)B_ * T_DE_ * U_);
  short* wen_hi = p;  p += 131072;                    // D*U shorts (256 KB)
  short* wen_lo = p;  p += 131072;
  short* wde_hi = p;  p += 131072;
  short* wde_lo = p;  p += 131072;

  wprep_kernel<<<dim3(128), 256, 0, stream>>>(
      w_en, w_de, wen_hi, wen_lo, wde_hi, wde_lo);
  proj_fused_kernel<<<dim3(640), 256, 0, stream>>>(
      en, de, wen_hi, wen_lo, wde_hi, wde_lo, Et, de_t);
  attn_mu_softmax_kernel<<<dim3(512), 512, 0, stream>>>(
      Et, de_t, nu, mask, out);
}

// Round 10
// 47.380 us; speedup vs baseline: 1.1938x; 1.1435x over previous
//
#include <hip/hip_runtime.h>
#include <cstddef>
#include <cstdint>

#define B_    8
#define T_EN_ 512
#define T_DE_ 128
#define D_    512
#define U_    256

// tanh(x) = 1 - 2/(exp2(C*x)+1), C = 2*log2(e)
#define TANH_C 2.8853900817779268f
#define L2E_   1.4426950408889634f
#define TANH_CLAMP 0.99999994f

typedef float f32x4 __attribute__((ext_vector_type(4)));
typedef float f32x2 __attribute__((ext_vector_type(2)));
typedef short s16x8 __attribute__((ext_vector_type(8)));

__device__ __forceinline__ float fast_tanh_clamped(float x) {
  const float e = __builtin_amdgcn_exp2f(x * TANH_C);
  float t = fmaf(-2.0f, __builtin_amdgcn_rcpf(e + 1.0f), 1.0f);
  return fminf(fmaxf(t, -TANH_CLAMP), TANH_CLAMP);
}

__device__ __forceinline__ f32x2 pk2(float s) { f32x2 v; v[0] = s; v[1] = s; return v; }

// split f32 -> bf16 hi (truncated) + bf16 lo (truncated remainder)
__device__ __forceinline__ void split_bf16(float x, short& hi, short& lo) {
  const unsigned u = __float_as_uint(x);
  hi = (short)(u >> 16);
  const float hf = __uint_as_float(u & 0xffff0000u);
  const float lf = x - hf;
  lo = (short)(__float_as_uint(lf) >> 16);
}

// ---------------------------------------------------------------------------
// K0: prepack w_en / w_de to bf16 hi/lo fragment planes (verified r5-r9).
// ---------------------------------------------------------------------------
__global__ __launch_bounds__(256) void wprep_kernel(
    const float* __restrict__ w_en, const float* __restrict__ w_de,
    short* __restrict__ wen_hi, short* __restrict__ wen_lo,
    short* __restrict__ wde_hi, short* __restrict__ wde_lo) {
  const int blk = blockIdx.x, tid = threadIdx.x;
  const bool is_en = blk < 64;
  const int wq = blk & 63;
  const int s = wq >> 2, USq = wq & 3;
  const int n = tid & 15, g = (tid >> 4) & 3;
  const int US = USq * 4 + (tid >> 6);
  const float* W = is_en ? w_en : w_de;
  short* ph = is_en ? wen_hi : wde_hi;
  short* pl = is_en ? wen_lo : wde_lo;
  s16x8 h8, l8;
  #pragma unroll
  for (int e = 0; e < 8; ++e) {
    const int k = s * 32 + g * 4 + (e & 3) + 16 * (e >> 2);
    short h, l;
    split_bf16(W[(size_t)k * U_ + US * 16 + n], h, l);
    h8[e] = h; l8[e] = l;
  }
  const size_t ub = ((size_t)(s * 16 + US) * 4 + g) * 16 + n;
  *(s16x8*)(ph + ub * 8) = h8;
  *(s16x8*)(pl + ub * 8) = l8;
}

// ---------------------------------------------------------------------------
// K1: fused projection (verified r9, unchanged).
// ---------------------------------------------------------------------------
__global__ __launch_bounds__(256) void proj_fused_kernel(
    const float* __restrict__ en, const float* __restrict__ de,
    const short* __restrict__ wen_hi, const short* __restrict__ wen_lo,
    const short* __restrict__ wde_hi, const short* __restrict__ wde_lo,
    float* __restrict__ Et, float* __restrict__ de_t) {
  __shared__ short xf_hi[16384];   // [s2i 32][lane 64][e 8] shorts, 32 KB
  __shared__ short xf_lo[16384];

  const int tid = threadIdx.x, lane = tid & 63, wv = tid >> 6;
  const int blk = blockIdx.x;
  const bool deb = blk < 128;
  const float* X;
  const short *Whi, *Wlo;
  int b = 0, i0, uq;
  if (deb) {
    const int jt = blk >> 2; uq = blk & 3; i0 = jt * 32;   // flat de rows
    X = de + (size_t)i0 * D_;
    Whi = wde_hi; Wlo = wde_lo;
  } else {
    const int y = blk - 128;
    b = y >> 6; i0 = ((y >> 2) & 15) * 32; uq = y & 3;
    X = en + ((size_t)b * T_EN_ + i0) * D_;
    Whi = wen_hi; Wlo = wen_lo;
  }

  {
    const int r = tid >> 3, kh = tid & 7;
    const int isub = r >> 4, n = r & 15;
    const float* src = X + (size_t)r * D_ + kh * 64;
    #pragma unroll
    for (int c = 0; c < 2; ++c) {
      const int s2i = (kh * 2 + c) * 2 + isub;
      float v[32];
      #pragma unroll
      for (int q = 0; q < 8; ++q) {
        const float4 f = *(const float4*)(src + c * 32 + q * 4);
        v[q * 4 + 0] = f.x; v[q * 4 + 1] = f.y;
        v[q * 4 + 2] = f.z; v[q * 4 + 3] = f.w;
      }
      #pragma unroll
      for (int g = 0; g < 4; ++g) {
        s16x8 h8, l8;
        #pragma unroll
        for (int e = 0; e < 8; ++e) {
          const int mm = (e >> 2) * 16 + g * 4 + (e & 3);
          short h, l;
          split_bf16(v[mm], h, l);
          h8[e] = h; l8[e] = l;
        }
        const int idx = ((s2i * 64 + g * 16 + n) * 8) ^ (((s2i >> 2) & 7) << 3);
        *(s16x8*)(xf_hi + idx) = h8;
        *(s16x8*)(xf_lo + idx) = l8;
      }
    }
  }
  __syncthreads();

  const int wvu = wv & 1, rh = wv >> 1;
  const int US0 = uq * 4 + wvu * 2;
  const int rl = lane >> 4, cl = lane & 15;
  f32x4 acc[2] = {};

  #pragma unroll 2
  for (int s = 0; s < 16; ++s) {
    const size_t o0 = ((size_t)(s * 16 + US0) * 64 + lane) * 8;
    const s16x8 wh0 = *(const s16x8*)(Whi + o0);
    const s16x8 wl0 = *(const s16x8*)(Wlo + o0);
    const s16x8 wh1 = *(const s16x8*)(Whi + o0 + 512);
    const s16x8 wl1 = *(const s16x8*)(Wlo + o0 + 512);
    const int s2 = s * 2 + rh;
    const int ei = ((s2 * 64 + lane) * 8) ^ (((s2 >> 2) & 7) << 3);
    const s16x8 eh = *(const s16x8*)(xf_hi + ei);
    const s16x8 el = *(const s16x8*)(xf_lo + ei);

    acc[0] = __builtin_amdgcn_mfma_f32_16x16x32_bf16(wh0, eh, acc[0], 0, 0, 0);
    acc[0] = __builtin_amdgcn_mfma_f32_16x16x32_bf16(wh0, el, acc[0], 0, 0, 0);
    acc[0] = __builtin_amdgcn_mfma_f32_16x16x32_bf16(wl0, eh, acc[0], 0, 0, 0);
    acc[1] = __builtin_amdgcn_mfma_f32_16x16x32_bf16(wh1, eh, acc[1], 0, 0, 0);
    acc[1] = __builtin_amdgcn_mfma_f32_16x16x32_bf16(wh1, el, acc[1], 0, 0, 0);
    acc[1] = __builtin_amdgcn_mfma_f32_16x16x32_bf16(wl1, eh, acc[1], 0, 0, 0);
  }

  #pragma unroll
  for (int us = 0; us < 2; ++us) {
    #pragma unroll
    for (int r = 0; r < 4; ++r) {
      const float t = fast_tanh_clamped(acc[us][r]);
      const int u = (US0 + us) * 16 + rl * 4 + r;
      const int rw = i0 + rh * 16 + cl;
      if (!deb) Et[((size_t)b * U_ + u) * T_EN_ + rw] = t;
      else      de_t[(size_t)rw * U_ + u] = t;
    }
  }
}

// ---------------------------------------------------------------------------
// K2 v5: mu = sum over u-PAIRS of (n1*d2 + n2*d1) / (d1*d2), where
//   n_i = fma(nu_i, E_i, nu_i*A_i), d_i = fma(A_i, E_i, 1)  [exact pairing of
//   the tanh-addition identity -> 1 rcp per 2 u-terms], with all non-rcp math
//   written as f32x2 (i-pairs) so clang emits v_pk_fma_f32 (2 f32/lane/instr).
// Same skeleton as verified v4: grid 512 = jg2*8 + b, 512 thr = 8 waves,
// wave (uq = w&3 -> 32 pairs, ih = w>>2 -> 256 i, 4 i/lane), partial mu in
// LDS, waves 0/1 do masked softmax.
// ---------------------------------------------------------------------------
__global__ __launch_bounds__(512) void attn_mu_softmax_kernel(
    const float* __restrict__ Et, const float* __restrict__ de_t,
    const float* __restrict__ nu, const int* __restrict__ mask,
    float* __restrict__ out) {
  __shared__ f32x4 Lp_s[2][U_ / 2];    // per (jl, pair): {A1, A2, nu1*A1, nu2*A2}
  __shared__ f32x2 nv2_s[U_ / 2];      // per pair: {nu1, nu2}
  __shared__ float mu_p[4][2][T_EN_];  // partial logits  16 KB

  const int tid  = threadIdx.x;
  const int lane = tid & 63;
  const int w    = tid >> 6;           // 0..7
  const int uq   = w & 3;
  const int ih   = w >> 2;
  const int b    = blockIdx.x & 7;
  const int jg   = blockIdx.x >> 3;    // 0..63
  const int j0   = jg * 2;

  // ---- prologue: per-(j, u-pair) constants ----
  if (tid < 256) {
    const int jp = tid >> 7, p = tid & 127;
    const float2 Av = *(const float2*)(de_t + (size_t)(b * T_DE_ + j0 + jp) * U_ + 2 * p);
    const float2 nv = *(const float2*)(nu + 2 * p);
    f32x4 L;
    L[0] = Av.x; L[1] = Av.y; L[2] = nv.x * Av.x; L[3] = nv.y * Av.y;
    Lp_s[jp][p] = L;
  } else if (tid < 384) {
    const int p = tid - 256;
    const float2 nv = *(const float2*)(nu + 2 * p);
    f32x2 n2; n2[0] = nv.x; n2[1] = nv.y;
    nv2_s[p] = n2;
  }
  __syncthreads();

  const int pb = uq * 32;              // first pair of this wave's 64-u range
  const float* __restrict__ Eb =
      Et + ((size_t)b * U_ + 2 * pb) * T_EN_ + ih * 256 + lane * 4;

  const f32x2 one2 = {1.0f, 1.0f};
  f32x2 a0A = {0.f, 0.f}, a0B = {0.f, 0.f};   // j0:  i-pair A (i0,i1), B (i2,i3)
  f32x2 a1A = {0.f, 0.f}, a1B = {0.f, 0.f};   // j0+1

  f32x4 L0a[2], L1a[2], L0b[2], L1b[2];
  f32x2 nva[2], nvb[2];
  float4 E1a[2], E2a[2], E1b[2], E2b[2];

#define LOADC(L0, L1, NV, E1, E2, P0)                                       \
  { _Pragma("unroll")                                                       \
    for (int c = 0; c < 2; ++c) {                                           \
      L0[c] = Lp_s[0][pb + (P0) + c];                                       \
      L1[c] = Lp_s[1][pb + (P0) + c];                                       \
      NV[c] = nv2_s[pb + (P0) + c];                                         \
      E1[c] = *(const float4*)(Eb + (size_t)(2 * ((P0) + c)) * T_EN_);      \
      E2[c] = *(const float4*)(Eb + (size_t)(2 * ((P0) + c) + 1) * T_EN_);  \
    } }

#define PAIR_J(L, e1, e2, nv1, nv2, ACC)                                    \
  {                                                                         \
    const f32x2 d1 = pk2(L[0]) * e1 + one2;                                 \
    const f32x2 d2 = pk2(L[1]) * e2 + one2;                                 \
    const f32x2 n1 = nv1 * e1 + pk2(L[2]);                                  \
    const f32x2 n2 = nv2 * e2 + pk2(L[3]);                                  \
    const f32x2 N  = n1 * d2 + n2 * d1;                                     \
    const f32x2 D  = d1 * d2;                                               \
    f32x2 r; r[0] = __builtin_amdgcn_rcpf(D[0]);                            \
             r[1] = __builtin_amdgcn_rcpf(D[1]);                            \
    ACC = N * r + ACC;                                                      \
  }

#define COMP(L0, L1, NV, E1, E2)                                            \
  { _Pragma("unroll")                                                       \
    for (int c = 0; c < 2; ++c) {                                           \
      f32x2 e1A; e1A[0] = E1[c].x; e1A[1] = E1[c].y;                        \
      f32x2 e1B; e1B[0] = E1[c].z; e1B[1] = E1[c].w;                        \
      f32x2 e2A; e2A[0] = E2[c].x; e2A[1] = E2[c].y;                        \
      f32x2 e2B; e2B[0] = E2[c].z; e2B[1] = E2[c].w;                        \
      const f32x2 nv1 = pk2(NV[c][0]);                                      \
      const f32x2 nv2 = pk2(NV[c][1]);                                      \
      PAIR_J(L0[c], e1A, e2A, nv1, nv2, a0A)                                \
      PAIR_J(L0[c], e1B, e2B, nv1, nv2, a0B)                                \
      PAIR_J(L1[c], e1A, e2A, nv1, nv2, a1A)                                \
      PAIR_J(L1[c], e1B, e2B, nv1, nv2, a1B)                                \
    } }

  LOADC(L0a, L1a, nva, E1a, E2a, 0)
  for (int p0 = 0; p0 < 32; p0 += 4) {
    LOADC(L0b, L1b, nvb, E1b, E2b, p0 + 2)
    COMP(L0a, L1a, nva, E1a, E2a)
    if (p0 + 4 < 32) LOADC(L0a, L1a, nva, E1a, E2a, p0 + 4)
    COMP(L0b, L1b, nvb, E1b, E2b)
  }
#undef LOADC
#undef PAIR_J
#undef COMP

  {
    float4 m0, m1;
    m0.x = a0A[0]; m0.y = a0A[1]; m0.z = a0B[0]; m0.w = a0B[1];
    m1.x = a1A[0]; m1.y = a1A[1]; m1.z = a1B[0]; m1.w = a1B[1];
    *(float4*)&mu_p[uq][0][ih * 256 + lane * 4] = m0;
    *(float4*)&mu_p[uq][1][ih * 256 + lane * 4] = m1;
  }
  __syncthreads();

  // ---- combine partials + masked softmax: waves 0/1, one j each ----
  if (w < 2) {
    const int jj = j0 + w;
    float vals[8];
    float mx = -3.0e38f;
    #pragma unroll
    for (int k = 0; k < 8; ++k) {
      const int i = lane + 64 * k;
      const float s = (mu_p[0][w][i] + mu_p[1][w][i]) +
                      (mu_p[2][w][i] + mu_p[3][w][i]);
      const float mi = (float)mask[b * T_EN_ + i];
      const float v = fmaf(mi - 1.0f, 1.0e6f, s);
      vals[k] = v;
      mx = fmaxf(mx, v);
    }
    #pragma unroll
    for (int off = 32; off; off >>= 1) mx = fmaxf(mx, __shfl_xor(mx, off, 64));
    float sum = 0.0f;
    #pragma unroll
    for (int k = 0; k < 8; ++k) {
      const float e = __builtin_amdgcn_exp2f((vals[k] - mx) * L2E_);
      vals[k] = e;
      sum += e;
    }
    #pragma unroll
    for (int off = 32; off; off >>= 1) sum += __shfl_xor(sum, off, 64);
    const float inv = __builtin_amdgcn_rcpf(sum);
    float* op = out + (size_t)(b * T_DE_ + jj) * T_EN_;
    #pragma unroll
    for (int k = 0; k < 8; ++k) op[lane + 64 * k] = vals[k] * inv;
  }
}

// ---------------------------------------------------------------------------
extern "C" void kernel_launch(void* const* d_in, const int* in_sizes, int n_in,
                              void* d_out, int out_size, void* d_ws, size_t ws_size,
                              hipStream_t stream) {
  const float* en   = (const float*)d_in[0];   // [B, T_EN, D]
  const float* de   = (const float*)d_in[1];   // [B, T_DE, D]
  const int*   mask = (const int*)d_in[2];     // [B, T_EN]
  const float* w_en = (const float*)d_in[3];   // [D, U]
  const float* w_de = (const float*)d_in[4];   // [D, U]
  const float* nu   = (const float*)d_in[5];   // [U, 1]
  float* out = (float*)d_out;                  // [B, T_DE, T_EN]

  // ws layout (6 MB)
  float* Et     = (float*)d_ws;                       // [B][U][T_EN]   4 MB
  float* de_t   = Et + (size_t)B_ * U_ * T_EN_;       // [B*T_DE][U]    1 MB
  short* p      = (short*)(de_t + (size_t)B_ * T_DE_ * U_);
  short* wen_hi = p;  p += 131072;                    // D*U shorts (256 KB)
  short* wen_lo = p;  p += 131072;
  short* wde_hi = p;  p += 131072;
  short* wde_lo = p;  p += 131072;

  wprep_kernel<<<dim3(128), 256, 0, stream>>>(
      w_en, w_de, wen_hi, wen_lo, wde_hi, wde_lo);
  proj_fused_kernel<<<dim3(640), 256, 0, stream>>>(
      en, de, wen_hi, wen_lo, wde_hi, wde_lo, Et, de_t);
  attn_mu_softmax_kernel<<<dim3(512), 512, 0, stream>>>(
      Et, de_t, nu, mask, out);
}

// Round 11
// 41.217 us; speedup vs baseline: 1.3723x; 1.1495x over previous
//
#include <hip/hip_runtime.h>
#include <cstddef>
#include <cstdint>

#define B_    8
#define T_EN_ 512
#define T_DE_ 128
#define D_    512
#define U_    256

// tanh(x) = 1 - 2/(exp2(C*x)+1), C = 2*log2(e)
#define TANH_C 2.8853900817779268f
#define L2E_   1.4426950408889634f
#define TANH_CLAMP 0.99999994f

typedef float f32x4 __attribute__((ext_vector_type(4)));
typedef float f32x2 __attribute__((ext_vector_type(2)));
typedef short s16x8 __attribute__((ext_vector_type(8)));

__device__ __forceinline__ float fast_tanh_clamped(float x) {
  const float e = __builtin_amdgcn_exp2f(x * TANH_C);
  float t = fmaf(-2.0f, __builtin_amdgcn_rcpf(e + 1.0f), 1.0f);
  return fminf(fmaxf(t, -TANH_CLAMP), TANH_CLAMP);
}

// split f32 -> bf16 hi (truncated) + bf16 lo (truncated remainder)
__device__ __forceinline__ void split_bf16(float x, short& hi, short& lo) {
  const unsigned u = __float_as_uint(x);
  hi = (short)(u >> 16);
  const float hf = __uint_as_float(u & 0xffff0000u);
  const float lf = x - hf;
  lo = (short)(__float_as_uint(lf) >> 16);
}

// ---------------------------------------------------------------------------
// Prepack (r5/r6-verified, verbatim): en/de/w_en/w_de -> bf16 hi/lo fragment
// planes. k-map in 32-k step s: k = s*32 + g*4 + (e&3) + 16*(e>>2), lane=g*16+n.
// ---------------------------------------------------------------------------
__global__ __launch_bounds__(256) void prepack_kernel(
    const float* __restrict__ en, const float* __restrict__ de,
    const float* __restrict__ w_en, const float* __restrict__ w_de,
    short* __restrict__ en_hi, short* __restrict__ en_lo,
    short* __restrict__ de_hi, short* __restrict__ de_lo,
    short* __restrict__ wen_hi, short* __restrict__ wen_lo,
    short* __restrict__ wde_hi, short* __restrict__ wde_lo) {
  const int blk = blockIdx.x;
  const int tid = threadIdx.x;
  float v[8];
  short* ph;
  short* pl;
  size_t ub;

  if (blk < 1280) {
    const int gu = blk * 256 + tid;
    const int n = gu & 15;
    const int g = (gu >> 4) & 3;
    const int s = (gu >> 6) & 15;
    const int rb = gu >> 10;
    const float* src;
    if (rb < 256) {
      const int b = rb >> 5, t = rb & 31;
      src = en + ((size_t)rb * 16 + n) * D_;
      ub = ((size_t)((b * 16 + s) * 32 + t) * 4 + g) * 16 + n;
      ph = en_hi; pl = en_lo;
    } else {
      const int t64 = rb - 256;
      src = de + ((size_t)t64 * 16 + n) * D_;
      ub = ((size_t)(s * 64 + t64) * 4 + g) * 16 + n;
      ph = de_hi; pl = de_lo;
    }
    const int kb = s * 32 + g * 4;
    const float4 fa = *(const float4*)(src + kb);
    const float4 fb = *(const float4*)(src + kb + 16);
    v[0] = fa.x; v[1] = fa.y; v[2] = fa.z; v[3] = fa.w;
    v[4] = fb.x; v[5] = fb.y; v[6] = fb.z; v[7] = fb.w;
  } else {
    const int wb = blk - 1280;
    const bool is_en = wb < 64;
    const int wq = wb & 63;
    const int s = wq >> 2, USq = wq & 3;
    const int n = tid & 15;
    const int g = (tid >> 4) & 3;
    const int US = USq * 4 + (tid >> 6);
    const float* W = is_en ? w_en : w_de;
    ph = is_en ? wen_hi : wde_hi;
    pl = is_en ? wen_lo : wde_lo;
    #pragma unroll
    for (int e = 0; e < 8; ++e) {
      const int k = s * 32 + g * 4 + (e & 3) + 16 * (e >> 2);
      v[e] = W[(size_t)k * U_ + US * 16 + n];
    }
    ub = ((size_t)(s * 16 + US) * 4 + g) * 16 + n;
  }

  s16x8 h8, l8;
  #pragma unroll
  for (int e = 0; e < 8; ++e) {
    short h, l;
    split_bf16(v[e], h, l);
    h8[e] = h; l8[e] = l;
  }
  *(s16x8*)(ph + ub * 8) = h8;
  *(s16x8*)(pl + ub * 8) = l8;
}

// ---------------------------------------------------------------------------
// K1: MFMA projections + tanh (r6-verified, verbatim). 640 blocks x 256 thr.
//  en blocks [0,512): (b, uh, it): 128u x 16i tile; wave = 32u x 16i (2 acc).
//  de blocks [512,640): (t64, uh): 16j x 128u tile; wave = 16j x 32u (2 acc).
// Pure-global frag loads (L2-hot), no LDS, no barriers, 2-stage prefetch.
// ---------------------------------------------------------------------------
__global__ __launch_bounds__(256) void mfma_proj_kernel(
    const short* __restrict__ en_hi, const short* __restrict__ en_lo,
    const short* __restrict__ de_hi, const short* __restrict__ de_lo,
    const short* __restrict__ wen_hi, const short* __restrict__ wen_lo,
    const short* __restrict__ wde_hi, const short* __restrict__ wde_lo,
    float* __restrict__ Et, float* __restrict__ de_t) {
  const int blk = blockIdx.x;
  const int tid = threadIdx.x;
  const int lane = tid & 63;
  const int wv = tid >> 6;
  const int rl = lane >> 4, cl = lane & 15;

  f32x4 acc[2] = {};
  s16x8 bufA[6], bufB[6];

  if (blk < 512) {
    const int b  = blk >> 6;
    const int uh = (blk >> 5) & 1;
    const int it = blk & 31;
    const int US0 = uh * 8 + wv * 2;

#define LOAD_EN(DST, S)                                                   \
    { const size_t oa0 = ((size_t)((S) * 16 + US0) * 64 + lane) * 8;      \
      const size_t ob  = ((size_t)((b * 16 + (S)) * 32 + it) * 64 + lane) * 8; \
      DST[0] = *(const s16x8*)(wen_hi + oa0);                             \
      DST[1] = *(const s16x8*)(wen_lo + oa0);                             \
      DST[2] = *(const s16x8*)(wen_hi + oa0 + 512);                       \
      DST[3] = *(const s16x8*)(wen_lo + oa0 + 512);                       \
      DST[4] = *(const s16x8*)(en_hi + ob);                               \
      DST[5] = *(const s16x8*)(en_lo + ob); }
#define MFMA_EN(S)                                                        \
    { acc[0] = __builtin_amdgcn_mfma_f32_16x16x32_bf16(S[0], S[4], acc[0], 0, 0, 0); \
      acc[0] = __builtin_amdgcn_mfma_f32_16x16x32_bf16(S[0], S[5], acc[0], 0, 0, 0); \
      acc[0] = __builtin_amdgcn_mfma_f32_16x16x32_bf16(S[1], S[4], acc[0], 0, 0, 0); \
      acc[1] = __builtin_amdgcn_mfma_f32_16x16x32_bf16(S[2], S[4], acc[1], 0, 0, 0); \
      acc[1] = __builtin_amdgcn_mfma_f32_16x16x32_bf16(S[2], S[5], acc[1], 0, 0, 0); \
      acc[1] = __builtin_amdgcn_mfma_f32_16x16x32_bf16(S[3], S[4], acc[1], 0, 0, 0); }

    LOAD_EN(bufA, 0)
    for (int s = 0; s < 16; s += 2) {
      LOAD_EN(bufB, s + 1)
      MFMA_EN(bufA)
      if (s + 2 < 16) LOAD_EN(bufA, s + 2)
      MFMA_EN(bufB)
    }
#undef LOAD_EN
#undef MFMA_EN

    #pragma unroll
    for (int us = 0; us < 2; ++us) {
      #pragma unroll
      for (int r = 0; r < 4; ++r) {
        const int u = (US0 + us) * 16 + rl * 4 + r;
        const int i = it * 16 + cl;
        Et[((size_t)b * U_ + u) * T_EN_ + i] = fast_tanh_clamped(acc[us][r]);
      }
    }
  } else {
    const int y = blk - 512;
    const int t64 = y >> 1;
    const int uh = y & 1;
    const int US0 = uh * 8 + wv * 2;

#define LOAD_DE(DST, S)                                                   \
    { const size_t oa = ((size_t)((S) * 64 + t64) * 64 + lane) * 8;       \
      const size_t ob = ((size_t)((S) * 16 + US0) * 64 + lane) * 8;       \
      DST[0] = *(const s16x8*)(de_hi + oa);                               \
      DST[1] = *(const s16x8*)(de_lo + oa);                               \
      DST[2] = *(const s16x8*)(wde_hi + ob);                              \
      DST[3] = *(const s16x8*)(wde_lo + ob);                              \
      DST[4] = *(const s16x8*)(wde_hi + ob + 512);                        \
      DST[5] = *(const s16x8*)(wde_lo + ob + 512); }
#define MFMA_DE(S)                                                        \
    { acc[0] = __builtin_amdgcn_mfma_f32_16x16x32_bf16(S[0], S[2], acc[0], 0, 0, 0); \
      acc[0] = __builtin_amdgcn_mfma_f32_16x16x32_bf16(S[0], S[3], acc[0], 0, 0, 0); \
      acc[0] = __builtin_amdgcn_mfma_f32_16x16x32_bf16(S[1], S[2], acc[0], 0, 0, 0); \
      acc[1] = __builtin_amdgcn_mfma_f32_16x16x32_bf16(S[0], S[4], acc[1], 0, 0, 0); \
      acc[1] = __builtin_amdgcn_mfma_f32_16x16x32_bf16(S[0], S[5], acc[1], 0, 0, 0); \
      acc[1] = __builtin_amdgcn_mfma_f32_16x16x32_bf16(S[1], S[4], acc[1], 0, 0, 0); }

    LOAD_DE(bufA, 0)
    for (int s = 0; s < 16; s += 2) {
      LOAD_DE(bufB, s + 1)
      MFMA_DE(bufA)
      if (s + 2 < 16) LOAD_DE(bufA, s + 2)
      MFMA_DE(bufB)
    }
#undef LOAD_DE
#undef MFMA_DE

    #pragma unroll
    for (int us = 0; us < 2; ++us) {
      #pragma unroll
      for (int r = 0; r < 4; ++r) {
        const int j = t64 * 16 + rl * 4 + r;
        const int u = (US0 + us) * 16 + cl;
        de_t[(size_t)j * U_ + u] = fast_tanh_clamped(acc[us][r]);
      }
    }
  }
}

// ---------------------------------------------------------------------------
// K2 v6: mu = sum over u-pairs of (n1*d2 + n2*d1)/(d1*d2)  [exact pairing of
// tanh-addition identity; 1 rcp / 2 u-terms], f32x4 over i (pk math).
// grid 256 = jg*8 + b (b pinned per XCD -> Et[b] L2-resident), 512 thr.
// Wave w = u-octant (32 u = 16 pairs); covers 4 j x 512 i (8 i/lane: quads
// at lane*4 and 256+lane*4). Partials mu_p[8][4][512] (64 KB; 1 blk/CU).
// E traffic halves vs v5 (128 MB); LDS consts ~1.1 B/term.
// ---------------------------------------------------------------------------
__global__ __launch_bounds__(512) void attn_mu_softmax_kernel(
    const float* __restrict__ Et, const float* __restrict__ de_t,
    const float* __restrict__ nu, const int* __restrict__ mask,
    float* __restrict__ out) {
  __shared__ f32x4 Lp_s[4][U_ / 2];     // [j-local][pair] {A1,A2,An1,An2} 8 KB
  __shared__ f32x2 nv2_s[U_ / 2];       // {nu1,nu2} per pair, 1 KB
  __shared__ float mu_p[8][4][T_EN_];   // partial logits, 64 KB

  const int tid  = threadIdx.x;
  const int lane = tid & 63;
  const int w    = tid >> 6;           // u-octant 0..7
  const int b    = blockIdx.x & 7;
  const int jg   = blockIdx.x >> 3;    // 0..31
  const int j0   = jg * 4;

  // ---- prologue: per-(j, u-pair) constants ----
  {
    const int jl = tid >> 7;           // 0..3
    const int p  = tid & 127;
    const float2 Av = *(const float2*)(de_t + (size_t)(b * T_DE_ + j0 + jl) * U_ + 2 * p);
    const float2 nv = *(const float2*)(nu + 2 * p);
    f32x4 L;
    L[0] = Av.x; L[1] = Av.y; L[2] = nv.x * Av.x; L[3] = nv.y * Av.y;
    Lp_s[jl][p] = L;
    if (tid < 128) {
      const float2 n2 = *(const float2*)(nu + 2 * tid);
      f32x2 v; v[0] = n2.x; v[1] = n2.y;
      nv2_s[tid] = v;
    }
  }
  __syncthreads();

  const int pb = w * 16;               // this wave's 16 pairs (32 u)
  const float* __restrict__ EbA =
      Et + ((size_t)b * U_ + 2 * pb) * T_EN_ + lane * 4;

  const f32x4 one4 = {1.f, 1.f, 1.f, 1.f};
  f32x4 accA[4] = {}, accB[4] = {};    // [j-local] x {i-quad A, B}

  f32x4 E1Aa, E1Ba, E2Aa, E2Ba, E1Ab, E1Bb, E2Ab, E2Bb;
  f32x4 La[4], Lb[4];
  f32x2 nva, nvb;

#define LOADP(SUF, P)                                                     \
  { const float* e1 = EbA + (size_t)(2 * (P)) * T_EN_;                    \
    const float* e2 = e1 + T_EN_;                                         \
    E1A##SUF = *(const f32x4*)(e1);                                       \
    E1B##SUF = *(const f32x4*)(e1 + 256);                                 \
    E2A##SUF = *(const f32x4*)(e2);                                       \
    E2B##SUF = *(const f32x4*)(e2 + 256);                                 \
    L##SUF[0] = Lp_s[0][pb + (P)];                                        \
    L##SUF[1] = Lp_s[1][pb + (P)];                                        \
    L##SUF[2] = Lp_s[2][pb + (P)];                                        \
    L##SUF[3] = Lp_s[3][pb + (P)];                                        \
    nv##SUF = nv2_s[pb + (P)]; }

#define COMPP(SUF)                                                        \
  { const f32x4 T1A = E1A##SUF * nv##SUF[0];                              \
    const f32x4 T1B = E1B##SUF * nv##SUF[0];                              \
    const f32x4 T2A = E2A##SUF * nv##SUF[1];                              \
    const f32x4 T2B = E2B##SUF * nv##SUF[1];                              \
    _Pragma("unroll")                                                     \
    for (int jl = 0; jl < 4; ++jl) {                                      \
      const f32x4 Lc = L##SUF[jl];                                        \
      { const f32x4 d1 = E1A##SUF * Lc[0] + one4;                         \
        const f32x4 d2 = E2A##SUF * Lc[1] + one4;                         \
        const f32x4 n1 = T1A + Lc[2];                                     \
        const f32x4 n2 = T2A + Lc[3];                                     \
        const f32x4 Nn = n1 * d2 + n2 * d1;                               \
        const f32x4 Dd = d1 * d2;                                         \
        f32x4 r;                                                          \
        r[0] = __builtin_amdgcn_rcpf(Dd[0]);                              \
        r[1] = __builtin_amdgcn_rcpf(Dd[1]);                              \
        r[2] = __builtin_amdgcn_rcpf(Dd[2]);                              \
        r[3] = __builtin_amdgcn_rcpf(Dd[3]);                              \
        accA[jl] = Nn * r + accA[jl]; }                                   \
      { const f32x4 d1 = E1B##SUF * Lc[0] + one4;                         \
        const f32x4 d2 = E2B##SUF * Lc[1] + one4;                         \
        const f32x4 n1 = T1B + Lc[2];                                     \
        const f32x4 n2 = T2B + Lc[3];                                     \
        const f32x4 Nn = n1 * d2 + n2 * d1;                               \
        const f32x4 Dd = d1 * d2;                                         \
        f32x4 r;                                                          \
        r[0] = __builtin_amdgcn_rcpf(Dd[0]);                              \
        r[1] = __builtin_amdgcn_rcpf(Dd[1]);                              \
        r[2] = __builtin_amdgcn_rcpf(Dd[2]);                              \
        r[3] = __builtin_amdgcn_rcpf(Dd[3]);                              \
        accB[jl] = Nn * r + accB[jl]; }                                   \
    } }

  LOADP(a, 0)
  for (int p0 = 0; p0 < 16; p0 += 2) {
    LOADP(b, p0 + 1)
    COMPP(a)
    if (p0 + 2 < 16) LOADP(a, p0 + 2)
    COMPP(b)
  }
#undef LOADP
#undef COMPP

  #pragma unroll
  for (int jl = 0; jl < 4; ++jl) {
    *(f32x4*)&mu_p[w][jl][lane * 4] = accA[jl];
    *(f32x4*)&mu_p[w][jl][256 + lane * 4] = accB[jl];
  }
  __syncthreads();

  // ---- combine 8 u-octant partials + masked softmax: waves 0..3, j each ----
  if (w < 4) {
    float vals[8];
    float mx = -3.0e38f;
    #pragma unroll
    for (int h = 0; h < 2; ++h) {
      f32x4 s = {0.f, 0.f, 0.f, 0.f};
      #pragma unroll
      for (int uo = 0; uo < 8; ++uo)
        s += *(const f32x4*)&mu_p[uo][w][h * 256 + lane * 4];
      const int4 mk = *(const int4*)(mask + b * T_EN_ + h * 256 + lane * 4);
      const float v0 = fmaf((float)mk.x - 1.f, 1.0e6f, s[0]);
      const float v1 = fmaf((float)mk.y - 1.f, 1.0e6f, s[1]);
      const float v2 = fmaf((float)mk.z - 1.f, 1.0e6f, s[2]);
      const float v3 = fmaf((float)mk.w - 1.f, 1.0e6f, s[3]);
      vals[h * 4 + 0] = v0; vals[h * 4 + 1] = v1;
      vals[h * 4 + 2] = v2; vals[h * 4 + 3] = v3;
      mx = fmaxf(mx, fmaxf(fmaxf(v0, v1), fmaxf(v2, v3)));
    }
    #pragma unroll
    for (int off = 32; off; off >>= 1) mx = fmaxf(mx, __shfl_xor(mx, off, 64));
    float sum = 0.0f;
    #pragma unroll
    for (int k = 0; k < 8; ++k) {
      const float e = __builtin_amdgcn_exp2f((vals[k] - mx) * L2E_);
      vals[k] = e;
      sum += e;
    }
    #pragma unroll
    for (int off = 32; off; off >>= 1) sum += __shfl_xor(sum, off, 64);
    const float inv = __builtin_amdgcn_rcpf(sum);
    float* op = out + (size_t)(b * T_DE_ + j0 + w) * T_EN_;
    #pragma unroll
    for (int h = 0; h < 2; ++h) {
      const float4 o = make_float4(vals[h * 4 + 0] * inv, vals[h * 4 + 1] * inv,
                                   vals[h * 4 + 2] * inv, vals[h * 4 + 3] * inv);
      *(float4*)(op + h * 256 + lane * 4) = o;
    }
  }
}

// ---------------------------------------------------------------------------
extern "C" void kernel_launch(void* const* d_in, const int* in_sizes, int n_in,
                              void* d_out, int out_size, void* d_ws, size_t ws_size,
                              hipStream_t stream) {
  const float* en   = (const float*)d_in[0];   // [B, T_EN, D]
  const float* de   = (const float*)d_in[1];   // [B, T_DE, D]
  const int*   mask = (const int*)d_in[2];     // [B, T_EN]
  const float* w_en = (const float*)d_in[3];   // [D, U]
  const float* w_de = (const float*)d_in[4];   // [D, U]
  const float* nu   = (const float*)d_in[5];   // [U, 1]
  float* out = (float*)d_out;                  // [B, T_DE, T_EN]

  // ws layout (16 MB; ws_size verified >= 16 MB by r5/r6 runs on this harness)
  float* Et   = (float*)d_ws;                  // [B][U][T_EN]  4 MB
  float* de_t = Et + (size_t)B_ * U_ * T_EN_;  // [B*T_DE][U]   1 MB
  short* p    = (short*)(de_t + (size_t)B_ * T_DE_ * U_);
  short* en_hi = p;                 p += 2097152;   // B*T_EN*D
  short* en_lo = p;                 p += 2097152;
  short* de_hi = p;                 p += 524288;    // B*T_DE*D
  short* de_lo = p;                 p += 524288;
  short* wen_hi = p;                p += 131072;    // D*U
  short* wen_lo = p;                p += 131072;
  short* wde_hi = p;                p += 131072;
  short* wde_lo = p;                p += 131072;

  prepack_kernel<<<dim3(1408), 256, 0, stream>>>(
      en, de, w_en, w_de, en_hi, en_lo, de_hi, de_lo,
      wen_hi, wen_lo, wde_hi, wde_lo);
  mfma_proj_kernel<<<dim3(640), 256, 0, stream>>>(
      en_hi, en_lo, de_hi, de_lo, wen_hi, wen_lo, wde_hi, wde_lo, Et, de_t);
  attn_mu_softmax_kernel<<<dim3(256), 512, 0, stream>>>(
      Et, de_t, nu, mask, out);
}